// Round 5
// baseline (51.931 us; speedup 1.0000x reference)
//
#include <hip/hip_runtime.h>
#include <math.h>

#define BD 8
#define SD 1024
#define ID 64
#define OD 128
#define NBD 6

// ---------------- prep: P (i,j,g)->(j,g,i); M,resW (i,j)->(j,i) --------------
__global__ __launch_bounds__(256) void prep_kernel(
    const float* __restrict__ P, const float* __restrict__ M,
    const float* __restrict__ resW,
    float* __restrict__ P2, float* __restrict__ MT, float* __restrict__ RT)
{
    const int idx = blockIdx.x * 256 + threadIdx.x;
    if (idx < OD * OD * NBD) {
        const int i = idx / (OD * NBD);
        const int r = idx - i * (OD * NBD);
        const int j = r / NBD;
        const int g = r - j * NBD;
        P2[(j * NBD + g) * OD + i] = P[idx];
    } else if (idx < OD * OD * NBD + OD * ID) {
        const int k = idx - OD * OD * NBD;
        const int i = k / ID, j = k - i * ID;
        MT[j * OD + i] = M[k];
    } else if (idx < OD * OD * NBD + 2 * OD * ID) {
        const int k = idx - OD * OD * NBD - OD * ID;
        const int i = k / ID, j = k - i * ID;
        RT[j * OD + i] = resW[k];
    }
}

// ---------------- Kernel A: weight-stationary proj + LN ---------------------
// 256 threads: i = t&127, mat = t>>7 (0 -> M/LN path, 1 -> residual path).
// Weights staged from transposed layout (coalesced); x via wave-uniform s_load.
__global__ __launch_bounds__(256) void ln_kernel(
    const float* __restrict__ seq,    // (8,1024,64)
    const float* __restrict__ MT,     // (64,128)  [j][i]
    const float* __restrict__ RT,     // (64,128)  [j][i]
    const float* __restrict__ gamma,
    const float* __restrict__ beta,
    float* __restrict__ xn_g,         // (1024,128,8) [s][j][b]
    float* __restrict__ out)          // (8,1024,128)  gets residual
{
    const int t   = threadIdx.x;
    const int s   = blockIdx.x;
    const int i   = t & 127;
    const int mat = t >> 7;           // wave-uniform
    __shared__ float red[2][16];

    // ---- stage weight column i (coalesced: lane i reads WT[j*128+i]) ----
    float w[ID];
    {
        const float* __restrict__ WT = (mat ? RT : MT) + i;
        #pragma unroll
        for (int j = 0; j < ID; ++j) w[j] = WT[j * OD];
    }
    const float gm = gamma[i];
    const float bt = beta[i];

    // ---- acc[b] = dot(x[b,s,:], w); x address wave-uniform -> s_load ----
    float acc[BD];
    #pragma unroll
    for (int b = 0; b < BD; ++b) {
        const float* __restrict__ xp = &seq[(b * SD + s) * ID];
        float a0 = 0.f, a1 = 0.f;
        #pragma unroll
        for (int j = 0; j < ID; j += 2) {
            a0 = fmaf(xp[j],     w[j],     a0);
            a1 = fmaf(xp[j + 1], w[j + 1], a1);
        }
        acc[b] = a0 + a1;
    }

    // ---- LN stats across 128 i-lanes (waves 0 & 1 only) ----
    if (mat == 0) {
        float sum[BD], ssq[BD];
        #pragma unroll
        for (int b = 0; b < BD; ++b) { sum[b] = acc[b]; ssq[b] = acc[b] * acc[b]; }
        #pragma unroll
        for (int m = 1; m < 64; m <<= 1) {
            #pragma unroll
            for (int b = 0; b < BD; ++b) {
                sum[b] += __shfl_xor(sum[b], m, 64);
                ssq[b] += __shfl_xor(ssq[b], m, 64);
            }
        }
        if ((t & 63) == 0) {
            const int wv = t >> 6;
            #pragma unroll
            for (int b = 0; b < BD; ++b) {
                red[wv][b]     = sum[b];
                red[wv][8 + b] = ssq[b];
            }
        }
    }
    __syncthreads();

    if (mat == 0) {
        float xn[BD];
        #pragma unroll
        for (int b = 0; b < BD; ++b) {
            const float sm = red[0][b] + red[1][b];
            const float sq = red[0][8 + b] + red[1][8 + b];
            const float mu = sm * (1.0f / OD);
            const float vr = sq * (1.0f / OD) - mu * mu;
            const float rstd = rsqrtf(vr + 1e-5f);
            xn[b] = (acc[b] - mu) * rstd * gm + bt;
        }
        float* __restrict__ dst = &xn_g[(s * OD + i) * BD];
        *(float4*)&dst[0] = make_float4(xn[0], xn[1], xn[2], xn[3]);
        *(float4*)&dst[4] = make_float4(xn[4], xn[5], xn[6], xn[7]);
    } else {
        #pragma unroll
        for (int b = 0; b < BD; ++b)
            out[(b * SD + s) * OD + i] = acc[b];
    }
}

// ---------------- Kernel B: Nk accumulation, out += Nk ----------------------
// 256 threads: il = t&63 (i-lane), jq = t>>6 = wave id (32 j each). NKG=2 s.
#define NKG 2
__global__ __launch_bounds__(256, 4) void nk_kernel(
    const float* __restrict__ P2,     // [j][g][i]
    const float* __restrict__ xn_g,   // (1024,128,8) [s][j][b]
    float* __restrict__ out)          // (8,1024,128)
{
    const int s0 = blockIdx.x * NKG;
    const int ih = blockIdx.y;
    const int t  = threadIdx.x;
    const int il = t & 63;
    const int i  = ih * 64 + il;
    const int jq = __builtin_amdgcn_readfirstlane(t >> 6);  // wave id, uniform

    __shared__ __align__(16) float xnl[NKG][OD][BD];  // 8 KB
    __shared__ float stage[4][ID][BD + 1];            // padded, conflict-free

    // ---- stage xn for this block's s-group into LDS (coalesced) ----
    for (int o = t; o < NKG * OD * BD; o += 256)
        ((float*)xnl)[o] = xn_g[s0 * OD * BD + o];
    __syncthreads();

    float acc[NKG][BD];
    #pragma unroll
    for (int ls = 0; ls < NKG; ++ls)
        #pragma unroll
        for (int b = 0; b < BD; ++b) acc[ls][b] = 0.f;

    const float pA = (float)(i * (OD * NBD) + 2);

    #pragma unroll 4
    for (int j = 0; j < 32; ++j) {
        const int jj = (jq << 5) + j;
        const float* __restrict__ Pp = &P2[(jj * NBD) * OD + i];  // lane-coalesced
        float Pv[NBD], rp[NBD];
        #pragma unroll
        for (int g = 0; g < NBD; ++g) {
            Pv[g] = Pp[g * OD];
            const float p = pA + (float)(jj * NBD + g);   // exact int in f32
            rp[g] = __builtin_amdgcn_rcpf(p);
        }
        #pragma unroll
        for (int ls = 0; ls < NKG; ++ls) {
            const float sf = (float)(s0 + ls);
            float wv = 0.f;
            #pragma unroll
            for (int g = 0; g < NBD; ++g) {
                const float fr = __builtin_amdgcn_fractf(sf * rp[g]); // revolutions
                wv = fmaf(Pv[g], __builtin_amdgcn_cosf(fr), wv);      // cos(2*pi*fr)
            }
            const float4 xlo = *(const float4*)&xnl[ls][jj][0];  // LDS broadcast
            const float4 xhi = *(const float4*)&xnl[ls][jj][4];
            acc[ls][0] = fmaf(xlo.x, wv, acc[ls][0]);
            acc[ls][1] = fmaf(xlo.y, wv, acc[ls][1]);
            acc[ls][2] = fmaf(xlo.z, wv, acc[ls][2]);
            acc[ls][3] = fmaf(xlo.w, wv, acc[ls][3]);
            acc[ls][4] = fmaf(xhi.x, wv, acc[ls][4]);
            acc[ls][5] = fmaf(xhi.y, wv, acc[ls][5]);
            acc[ls][6] = fmaf(xhi.z, wv, acc[ls][6]);
            acc[ls][7] = fmaf(xhi.w, wv, acc[ls][7]);
        }
    }

    // ---- reduce 4 jq partials, out += Nk ----
    #pragma unroll
    for (int ls = 0; ls < NKG; ++ls) {
        __syncthreads();
        #pragma unroll
        for (int b = 0; b < BD; ++b) stage[jq][il][b] = acc[ls][b];
        __syncthreads();
        #pragma unroll
        for (int o = t; o < ID * BD; o += 256) {
            const int ii = o & 63;
            const int b  = o >> 6;
            const float v = stage[0][ii][b] + stage[1][ii][b]
                          + stage[2][ii][b] + stage[3][ii][b];
            out[(b * SD + (s0 + ls)) * OD + ih * 64 + ii] += v;
        }
    }
}

extern "C" void kernel_launch(void* const* d_in, const int* in_sizes, int n_in,
                              void* d_out, int out_size, void* d_ws, size_t ws_size,
                              hipStream_t stream) {
    const float* seq   = (const float*)d_in[0];
    const float* M     = (const float*)d_in[1];
    const float* P     = (const float*)d_in[2];
    const float* resW  = (const float*)d_in[3];
    const float* gamma = (const float*)d_in[4];
    const float* beta  = (const float*)d_in[5];
    float* out = (float*)d_out;

    float* xn_g = (float*)d_ws;                    // 4 MB
    float* P2   = xn_g + SD * OD * BD;             // 384 KB
    float* MT   = P2 + OD * OD * NBD;              // 32 KB
    float* RT   = MT + OD * ID;                    // 32 KB

    const int prep_elems = OD * OD * NBD + 2 * OD * ID;
    prep_kernel<<<dim3((prep_elems + 255) / 256), dim3(256), 0, stream>>>(
        P, M, resW, P2, MT, RT);
    ln_kernel<<<dim3(SD), dim3(256), 0, stream>>>(seq, MT, RT, gamma, beta,
                                                  xn_g, out);
    nk_kernel<<<dim3(SD / NKG, 2), dim3(256), 0, stream>>>(P2, xn_g, out);
}

// Round 6
// 51.772 us; speedup vs baseline: 1.0031x; 1.0031x over previous
//
#include <hip/hip_runtime.h>
#include <math.h>

#define BD 8
#define SD 1024
#define ID 64
#define OD 128
#define NBD 6
#define NGP 3          // g-pairs per j
#define SQ  4          // s per nk block

// ---- prep: P2c[(j*3+gp)*128+i] = {P[i,j,2gp], 1/p, P[i,j,2gp+1], 1/p'} ; MT/RT
__global__ __launch_bounds__(256) void prep_kernel(
    const float* __restrict__ P, const float* __restrict__ M,
    const float* __restrict__ resW,
    float4* __restrict__ P2c, float* __restrict__ MT, float* __restrict__ RT)
{
    const int idx = blockIdx.x * 256 + threadIdx.x;
    const int NP4 = OD * OD * NGP;                 // 49152
    if (idx < NP4) {
        const int i  = idx & 127;
        const int e  = idx >> 7;                   // j*3+gp
        const int j  = e / NGP;
        const int gp = e - j * NGP;
        const int g0 = gp * 2;
        const int base = i * (OD * NBD) + j * NBD; // P index base & period base
        float4 v;
        v.x = P[base + g0];
        v.y = 1.0f / (float)(base + g0 + 2);
        v.z = P[base + g0 + 1];
        v.w = 1.0f / (float)(base + g0 + 3);
        P2c[idx] = v;
    } else if (idx < NP4 + OD * ID) {
        const int k = idx - NP4;
        const int i = k / ID, j = k - i * ID;
        MT[j * OD + i] = M[k];
    } else if (idx < NP4 + 2 * OD * ID) {
        const int k = idx - NP4 - OD * ID;
        const int i = k / ID, j = k - i * ID;
        RT[j * OD + i] = resW[k];
    }
}

// ---- Kernel A: weight-stationary proj + LN -> xn_g ; residual -> out -------
__global__ __launch_bounds__(256) void ln_kernel(
    const float* __restrict__ seq,    // (8,1024,64)
    const float* __restrict__ MT,     // (64,128) [j][i]
    const float* __restrict__ RT,     // (64,128) [j][i]
    const float* __restrict__ gamma,
    const float* __restrict__ beta,
    float* __restrict__ xn_g,         // (1024,128,8) [s][j][b]
    float* __restrict__ out)          // (8,1024,128) gets residual
{
    const int t   = threadIdx.x;
    const int s   = blockIdx.x;
    const int i   = t & 127;
    const int mat = t >> 7;           // wave-uniform
    __shared__ float red[2][16];

    float w[ID];
    {
        const float* __restrict__ WT = (mat ? RT : MT) + i;
        #pragma unroll
        for (int j = 0; j < ID; ++j) w[j] = WT[j * OD];   // coalesced
    }
    const float gm = gamma[i];
    const float bt = beta[i];

    float acc[BD];
    #pragma unroll
    for (int b = 0; b < BD; ++b) {
        const float* __restrict__ xp = &seq[(b * SD + s) * ID];  // uniform -> s_load
        float a0 = 0.f, a1 = 0.f;
        #pragma unroll
        for (int j = 0; j < ID; j += 2) {
            a0 = fmaf(xp[j],     w[j],     a0);
            a1 = fmaf(xp[j + 1], w[j + 1], a1);
        }
        acc[b] = a0 + a1;
    }

    if (mat == 0) {
        float sum[BD], ssq[BD];
        #pragma unroll
        for (int b = 0; b < BD; ++b) { sum[b] = acc[b]; ssq[b] = acc[b] * acc[b]; }
        #pragma unroll
        for (int m = 1; m < 64; m <<= 1) {
            #pragma unroll
            for (int b = 0; b < BD; ++b) {
                sum[b] += __shfl_xor(sum[b], m, 64);
                ssq[b] += __shfl_xor(ssq[b], m, 64);
            }
        }
        if ((t & 63) == 0) {
            const int wv = t >> 6;
            #pragma unroll
            for (int b = 0; b < BD; ++b) {
                red[wv][b]     = sum[b];
                red[wv][8 + b] = ssq[b];
            }
        }
    }
    __syncthreads();

    if (mat == 0) {
        float xn[BD];
        #pragma unroll
        for (int b = 0; b < BD; ++b) {
            const float sm = red[0][b] + red[1][b];
            const float sq = red[0][8 + b] + red[1][8 + b];
            const float mu = sm * (1.0f / OD);
            const float vr = sq * (1.0f / OD) - mu * mu;
            const float rstd = rsqrtf(vr + 1e-5f);
            xn[b] = (acc[b] - mu) * rstd * gm + bt;
        }
        float* __restrict__ dst = &xn_g[(s * OD + i) * BD];
        *(float4*)&dst[0] = make_float4(xn[0], xn[1], xn[2], xn[3]);
        *(float4*)&dst[4] = make_float4(xn[4], xn[5], xn[6], xn[7]);
    } else {
        #pragma unroll
        for (int b = 0; b < BD; ++b)
            out[(b * SD + s) * OD + i] = acc[b];
    }
}

// ---- Kernel B: Nk, out += Nk -----------------------------------------------
// 512 threads: il=t&63 (i-lane), wid=t>>6: jh=wid&1 (j-half), ls=wid>>1 (s of 4).
// Inner loop: 3 coalesced float4 {P,1/p} loads, fract+cos+fma only. One barrier.
__global__ __launch_bounds__(512, 4) void nk_kernel(
    const float4* __restrict__ P2c,   // [(j*3+gp)*128 + i]
    const float* __restrict__ xn_g,   // (1024,128,8) [s][j][b]
    float* __restrict__ out)          // (8,1024,128)
{
    const int s0  = blockIdx.x * SQ;
    const int ih  = blockIdx.y;
    const int t   = threadIdx.x;
    const int il  = t & 63;
    const int wid = __builtin_amdgcn_readfirstlane(t >> 6);  // 0..7, uniform
    const int jh  = wid & 1;
    const int ls  = wid >> 1;
    const int i   = ih * 64 + il;
    const float sf = (float)(s0 + ls);

    __shared__ float stage[SQ][64][BD + 1];   // padded, conflict-free

    float acc[BD];
    #pragma unroll
    for (int b = 0; b < BD; ++b) acc[b] = 0.f;

    const int j0 = jh * 64;
    #pragma unroll 2
    for (int j = 0; j < 64; ++j) {
        const int jj = j0 + j;
        const float* __restrict__ xp = &xn_g[((s0 + ls) * OD + jj) * BD]; // uniform
        const float4* __restrict__ Pp = &P2c[(jj * NGP) * OD + i];        // coalesced
        float wv = 0.f;
        #pragma unroll
        for (int gp = 0; gp < NGP; ++gp) {
            const float4 pv = Pp[gp * OD];
            const float f0 = __builtin_amdgcn_fractf(sf * pv.y);  // revolutions
            const float f1 = __builtin_amdgcn_fractf(sf * pv.w);
            wv = fmaf(pv.x, __builtin_amdgcn_cosf(f0), wv);       // cos(2*pi*f)
            wv = fmaf(pv.z, __builtin_amdgcn_cosf(f1), wv);
        }
        #pragma unroll
        for (int b = 0; b < BD; ++b)
            acc[b] = fmaf(xp[b], wv, acc[b]);
    }

    if (jh) {
        #pragma unroll
        for (int b = 0; b < BD; ++b) stage[ls][il][b] = acc[b];
    }
    __syncthreads();
    if (!jh) {
        #pragma unroll
        for (int b = 0; b < BD; ++b)
            out[(b * SD + (s0 + ls)) * OD + i] += acc[b] + stage[ls][il][b];
    }
}

extern "C" void kernel_launch(void* const* d_in, const int* in_sizes, int n_in,
                              void* d_out, int out_size, void* d_ws, size_t ws_size,
                              hipStream_t stream) {
    const float* seq   = (const float*)d_in[0];
    const float* M     = (const float*)d_in[1];
    const float* P     = (const float*)d_in[2];
    const float* resW  = (const float*)d_in[3];
    const float* gamma = (const float*)d_in[4];
    const float* beta  = (const float*)d_in[5];
    float* out = (float*)d_out;

    float*  xn_g = (float*)d_ws;                        // 4 MB
    float4* P2c  = (float4*)(xn_g + SD * OD * BD);      // 768 KB
    float*  MT   = (float*)(P2c + OD * OD * NGP);       // 32 KB
    float*  RT   = MT + OD * ID;                        // 32 KB

    const int prep_elems = OD * OD * NGP + 2 * OD * ID; // 65536
    prep_kernel<<<dim3(prep_elems / 256), dim3(256), 0, stream>>>(
        P, M, resW, P2c, MT, RT);
    ln_kernel<<<dim3(SD), dim3(256), 0, stream>>>(seq, MT, RT, gamma, beta,
                                                  xn_g, out);
    nk_kernel<<<dim3(SD / SQ, 2), dim3(512), 0, stream>>>(P2c, xn_g, out);
}